// Round 11
// baseline (796.270 us; speedup 1.0000x reference)
//
#include <hip/hip_runtime.h>
#include <hip/hip_bf16.h>
#include <cstdint>
#include <cstddef>

#define F_IN 128
#define HC12 256   // HEADS*HID for layers 1/2
#define HC3 484    // OUT_HEADS*N_CLS for layer 3
#define NCLS 121

typedef unsigned short u16;
typedef unsigned int u32;
typedef __attribute__((ext_vector_type(8))) short short8;
typedef __attribute__((ext_vector_type(4))) float float4v;

static __device__ __forceinline__ float lrelu(float x) { return x > 0.f ? x : 0.2f * x; }

static __device__ __forceinline__ u16 f2bf(float f) {
    union { float f; unsigned u; } v; v.f = f;
    unsigned r = v.u + 0x7FFF + ((v.u >> 16) & 1);
    return (u16)(r >> 16);
}
static __device__ __forceinline__ float bf2f(u16 h) {
    union { unsigned u; float f; } v; v.u = ((unsigned)h) << 16;
    return v.f;
}
static __device__ __forceinline__ u32 pk_bf16(float a, float b) {
    float2 f; f.x = a; f.y = b;
    union { __hip_bfloat162 b2; u32 u; } cv;
    cv.b2 = __float22bfloat162_rn(f);
    return cv.u;
}

// ---------------- CSR build ----------------
__global__ void hist_kernel(const int* __restrict__ dst, int* __restrict__ deg, int E) {
    int e = blockIdx.x * 256 + threadIdx.x;
    if (e < E) atomicAdd(&deg[dst[e]], 1);
}

__global__ __launch_bounds__(1024) void scan_kernel(const int* __restrict__ deg,
                                                    int* __restrict__ rowp, int N) {
    __shared__ int swave[16];
    __shared__ int s_carry;
    int tid = threadIdx.x;
    int w = tid >> 6, lane = tid & 63;
    if (tid == 0) { rowp[0] = 0; s_carry = 0; }
    __syncthreads();
    for (int base = 0; base < N; base += 4096) {
        int i0 = base + tid * 4;
        int v0 = (i0     < N) ? deg[i0]     : 0;
        int v1 = (i0 + 1 < N) ? deg[i0 + 1] : 0;
        int v2 = (i0 + 2 < N) ? deg[i0 + 2] : 0;
        int v3 = (i0 + 3 < N) ? deg[i0 + 3] : 0;
        int t = v0 + v1 + v2 + v3;
        int sc = t;
#pragma unroll
        for (int off = 1; off < 64; off <<= 1) {
            int u = __shfl_up(sc, off, 64);
            if (lane >= off) sc += u;
        }
        if (lane == 63) swave[w] = sc;
        __syncthreads();
        if (w == 0) {
            int ws = (lane < 16) ? swave[lane] : 0;
#pragma unroll
            for (int off = 1; off < 16; off <<= 1) {
                int u = __shfl_up(ws, off, 64);
                if (lane >= off) ws += u;
            }
            if (lane < 16) swave[lane] = ws;
        }
        __syncthreads();
        int carry = s_carry;
        int tb = carry + ((w > 0) ? swave[w - 1] : 0) + sc - t;
        if (i0     < N) rowp[i0 + 1] = tb + v0;
        if (i0 + 1 < N) rowp[i0 + 2] = tb + v0 + v1;
        if (i0 + 2 < N) rowp[i0 + 3] = tb + v0 + v1 + v2;
        if (i0 + 3 < N) rowp[i0 + 4] = tb + t;
        __syncthreads();
        if (tid == 1023) s_carry = carry + swave[15];
        __syncthreads();
    }
}

__global__ void scatter_kernel(const int* __restrict__ src, const int* __restrict__ dst,
                               const int* __restrict__ rowp, int* __restrict__ cur,
                               int* __restrict__ col, int E) {
    int e = blockIdx.x * 256 + threadIdx.x;
    if (e < E) {
        int d = dst[e];
        int pos = rowp[d] + atomicAdd(&cur[d], 1);
        col[pos] = src[e];
    }
}

// ---------------- fused weight transpose -> bf16 ----------------
__global__ void splitT_all_kernel(const float* W1, const float* l1W, const float* W2,
                                  const float* W3, const float* l3W,
                                  u16* C1h, u16* C2h, u16* C3h) {
    int i = blockIdx.x * 256 + threadIdx.x;
    const float* B; u16* hi; int K, N;
    if (i < 32768)       { B = W1;  hi = C1h;             K = 128; N = 256; }
    else if (i < 65536)  { B = l1W; hi = C1h + 256 * 128; K = 128; N = 256; i -= 32768; }
    else if (i < 131072) { B = W2;  hi = C2h;             K = 256; N = 256; i -= 65536; }
    else if (i < 254976) { B = W3;  hi = C3h;             K = 256; N = 484; i -= 131072; }
    else if (i < 285952) { B = l3W; hi = C3h + 484 * 256; K = 256; N = 121; i -= 254976; }
    else return;
    int n = i % N, k = i / N;
    hi[(size_t)n * K + k] = f2bf(B[(size_t)k * N + n]);
}

// ---------------- fp32 -> bf16 convert (x) ----------------
__global__ void cvt_bf16_kernel(const float* __restrict__ in, u32* __restrict__ out, int npairs) {
    int i = blockIdx.x * 256 + threadIdx.x;
    if (i < npairs) {
        float2 f = *(const float2*)&in[2 * i];
        out[i] = pk_bf16(f.x, f.y);
    }
}

// ---------------- pure-bf16 MFMA GEMM, 128x128 tile, LDS-coalesced bf16 epilogue -----
// A: bf16 [M][K]; BT: bf16 [Ntot][K]. Staging = pure uint4 copies.
// cols [0,Nb) -> bf16 Cb via LDS-staged coalesced u32 writes;
// cols [Nb,Ntot) -> fp32 Cf + biasf (direct, line-aligned).
#define BM 128
#define BN 128
#define BK 32
#define LDA 40
#define TLW 130   // epilogue tile row stride (u16), padded vs 128 to break bank aliasing

__global__ __launch_bounds__(256, 4) void gemm_bf16(const u16* __restrict__ A,
                                                    const u16* __restrict__ BT,
                                                    int M, int K, int Ntot,
                                                    int nx, int ny,
                                                    int Nb, u16* __restrict__ Cb, int strideB,
                                                    float* __restrict__ Cf,
                                                    const float* __restrict__ biasf, int strideF) {
    __shared__ __align__(16) u16 smem[BM * LDA + BN * LDA];   // 20480 B; reused by epilogue
    u16* sA = smem;
    u16* sB = smem + BM * LDA;
    int tid = threadIdx.x;
    int wave = tid >> 6, lane = tid & 63;
    int wr = wave >> 1, wc = wave & 1;

    // XCD-aware block swizzle: col-blocks of one row-tile land 8 apart (same XCD)
    int bid = blockIdx.x;
    int G = nx * 8;
    int g = bid / G;
    int rem = ny - g * 8;
    int rb, cb;
    if (rem >= 8) {
        int r = bid - g * G;
        rb = g * 8 + (r & 7);
        cb = r >> 3;
    } else {
        int t = bid - g * G;
        rb = g * 8 + t % rem;
        cb = t / rem;
    }
    int m0 = rb * BM, n0 = cb * BN;

    int fm = lane & 15;
    int q = lane >> 4;
    int r0 = tid >> 2;
    int c0 = (tid & 3) * 8;

    float4v acc[4][4];
#pragma unroll
    for (int i = 0; i < 4; i++)
#pragma unroll
        for (int j = 0; j < 4; j++) acc[i][j] = (float4v){0.f, 0.f, 0.f, 0.f};

    const uint4 zero4 = {0u, 0u, 0u, 0u};
    uint4 pa[2], pb[2];

#pragma unroll
    for (int j = 0; j < 2; j++) {
        int gr = m0 + r0 + j * 64;
        pa[j] = (gr < M) ? *(const uint4*)&A[(size_t)gr * K + c0] : zero4;
        int gn = n0 + r0 + j * 64;
        pb[j] = (gn < Ntot) ? *(const uint4*)&BT[(size_t)gn * K + c0] : zero4;
    }

    for (int kc = 0; kc < K; kc += BK) {
#pragma unroll
        for (int j = 0; j < 2; j++) {
            int row = r0 + j * 64;
            *(uint4*)&sA[row * LDA + c0] = pa[j];
            *(uint4*)&sB[row * LDA + c0] = pb[j];
        }
        __syncthreads();

        int kn = kc + BK;
        if (kn < K) {
#pragma unroll
            for (int j = 0; j < 2; j++) {
                int gr = m0 + r0 + j * 64;
                pa[j] = (gr < M) ? *(const uint4*)&A[(size_t)gr * K + kn + c0] : zero4;
                int gn = n0 + r0 + j * 64;
                pb[j] = (gn < Ntot) ? *(const uint4*)&BT[(size_t)gn * K + kn + c0] : zero4;
            }
        }

        short8 ah[4];
#pragma unroll
        for (int mi = 0; mi < 4; mi++) {
            int row = wr * 64 + mi * 16 + fm;
            ah[mi] = *(const short8*)&sA[row * LDA + q * 8];
        }
#pragma unroll
        for (int ni = 0; ni < 4; ni++) {
            int nn = wc * 64 + ni * 16 + fm;
            short8 bh = *(const short8*)&sB[nn * LDA + q * 8];
#pragma unroll
            for (int mi = 0; mi < 4; mi++)
                acc[mi][ni] = __builtin_amdgcn_mfma_f32_16x16x32_bf16(ah[mi], bh, acc[mi][ni], 0, 0, 0);
        }
        __syncthreads();
    }

    // ---- epilogue ----
    // bf16 width of this block (may be 0, partial, or 128); always even
    int Wb = Nb - n0;
    if (Wb < 0) Wb = 0;
    if (Wb > BN) Wb = BN;
    u16* tile = smem;   // 64 x TLW u16 = 8320 u16 <= 10240 available

#pragma unroll
    for (int h = 0; h < 2; h++) {
        __syncthreads();
        if (wr == h) {
#pragma unroll
            for (int mi = 0; mi < 4; mi++) {
#pragma unroll
                for (int ni = 0; ni < 4; ni++) {
                    int col = wc * 64 + ni * 16 + fm;
                    int colg = n0 + col;
#pragma unroll
                    for (int r = 0; r < 4; r++) {
                        int rloc = mi * 16 + q * 4 + r;      // 0..63 within half
                        float v = acc[mi][ni][r];
                        if (colg < Nb) {
                            tile[rloc * TLW + col] = f2bf(v);
                        } else if (colg < Ntot) {
                            int rowg = m0 + h * 64 + rloc;
                            if (rowg < M) {
                                int cf = colg - Nb;
                                Cf[(size_t)rowg * strideF + cf] = v + biasf[cf];
                            }
                        }
                    }
                }
            }
        }
        __syncthreads();
        if (Wb > 0) {
            int rr = tid >> 2;        // 0..63
            int part = tid & 3;       // 0..3
            int rowg = m0 + h * 64 + rr;
            if (rowg < M) {
                u32* dstp = (u32*)&Cb[(size_t)rowg * strideB + n0];
                const u32* srcp = (const u32*)&tile[rr * TLW];
                int nw = Wb >> 1;
                for (int i = part; i < nw; i += 4) dstp[i] = srcp[i];
            }
        }
    }
}

// ---------------- per-node attention coefficients (bf16 xh) ----------------
__global__ __launch_bounds__(256) void alpha_kernel(const u16* __restrict__ xh,
                                                    const float* __restrict__ a_s,
                                                    const float* __restrict__ a_d,
                                                    float* __restrict__ as_o,
                                                    float* __restrict__ ad_o, int C) {
    int n = blockIdx.x;
    int w = threadIdx.x >> 6, lane = threadIdx.x & 63;
    const u16* row = xh + (size_t)n * 4 * C + (size_t)w * C;
    float ss = 0.f, sd = 0.f;
    for (int c = lane; c < C; c += 64) {
        float v = bf2f(row[c]);
        ss += v * a_s[w * C + c];
        sd += v * a_d[w * C + c];
    }
    for (int o = 32; o; o >>= 1) {
        ss += __shfl_xor(ss, o, 64);
        sd += __shfl_xor(sd, o, 64);
    }
    if (!lane) {
        as_o[n * 4 + w] = ss;
        ad_o[n * 4 + w] = sd;
    }
}

// ---------------- fused softmax stats + per-edge alpha ----------------
__global__ __launch_bounds__(256) void stats_alpha_kernel(const int* __restrict__ rowp,
                                                          const int* __restrict__ col,
                                                          const float* __restrict__ asrc,
                                                          const float* __restrict__ adst,
                                                          float* __restrict__ alphaE, int N) {
    int i = blockIdx.x * 256 + threadIdx.x;
    if (i >= N * 4) return;
    int n = i >> 2, h = i & 3;
    int r0 = rowp[n], r1 = rowp[n + 1];
    float ad = adst[i];
    float m = -3.4e38f, s = 0.f;
    for (int e = r0; e < r1; e++) {
        int sc = col[e];
        float l = lrelu(asrc[sc * 4 + h] + ad);
        float nm = fmaxf(m, l);
        s = s * __expf(m - nm) + __expf(l - nm);
        m = nm;
    }
    float rd = 1.f / (s + 1e-16f);
    for (int e = r0; e < r1; e++) {
        int sc = col[e];
        float l = lrelu(asrc[sc * 4 + h] + ad);
        alphaE[(size_t)e * 4 + h] = __expf(l - m) * rd;
    }
}

// ---------------- gather+FMA aggregate, HC=256 (layers 1/2) ----------------
// out (fp32) and outb (bf16) are each optional. res/out may alias.
__global__ __launch_bounds__(256) void agg_kernel_256(const u16* __restrict__ xh,
                                                      const int* __restrict__ rowp,
                                                      const int* __restrict__ col,
                                                      const float* __restrict__ alphaE,
                                                      const float* __restrict__ bias,
                                                      const float* res,
                                                      float* out, u16* outb) {
    int n = blockIdx.x, tid = threadIdx.x;
    int r0 = rowp[n], deg = rowp[n + 1] - r0;
    __shared__ int s_src[64];
    __shared__ float s_al[64][4];
    __shared__ float s_part[4][HC12];
    int g = tid >> 6;
    int sub = tid & 63;
    int c = sub * 4;
    int h = sub >> 4;
    float a0 = 0.f, a1 = 0.f, a2 = 0.f, a3 = 0.f;
    for (int kb = 0; kb < deg; kb += 64) {
        int cn = min(64, deg - kb);
        __syncthreads();
        if (tid < cn) s_src[tid] = col[r0 + kb + tid];
        for (int idx = tid; idx < cn * 4; idx += 256)
            s_al[idx >> 2][idx & 3] = alphaE[(size_t)(r0 + kb) * 4 + idx];
        __syncthreads();
#pragma unroll 4
        for (int kk = g; kk < cn; kk += 4) {
            uint2 v = *(const uint2*)&xh[(size_t)s_src[kk] * HC12 + c];
            float al = s_al[kk][h];
            a0 += al * bf2f((u16)(v.x & 0xffff));
            a1 += al * bf2f((u16)(v.x >> 16));
            a2 += al * bf2f((u16)(v.y & 0xffff));
            a3 += al * bf2f((u16)(v.y >> 16));
        }
    }
    s_part[g][c] = a0; s_part[g][c + 1] = a1; s_part[g][c + 2] = a2; s_part[g][c + 3] = a3;
    __syncthreads();
    float v = s_part[0][tid] + s_part[1][tid] + s_part[2][tid] + s_part[3][tid]
              + bias[tid] + res[(size_t)n * HC12 + tid];
    float o = v > 0.f ? v : expm1f(v);
    if (out)  out[(size_t)n * HC12 + tid] = o;
    if (outb) outb[(size_t)n * HC12 + tid] = f2bf(o);
}

// ---------------- layer 3 gather: HC=484, mean heads + b3 + lin3 -> d_out ----------------
__global__ __launch_bounds__(256) void agg_out_kernel(const u16* __restrict__ xh,
                                                      const int* __restrict__ rowp,
                                                      const int* __restrict__ col,
                                                      const float* __restrict__ alphaE,
                                                      const float* __restrict__ b3,
                                                      const float* __restrict__ lin3,
                                                      float* __restrict__ out) {
    int n = blockIdx.x, tid = threadIdx.x;
    int r0 = rowp[n], deg = rowp[n + 1] - r0;
    __shared__ int s_src[64];
    __shared__ float s_al[64][4];
    __shared__ float s_out[HC3];
    bool act = tid < 242;
    int c0 = 2 * tid, c1 = c0 + 1;
    int h0 = c0 >= 363 ? 3 : (c0 >= 242 ? 2 : (c0 >= 121 ? 1 : 0));
    int h1 = c1 >= 363 ? 3 : (c1 >= 242 ? 2 : (c1 >= 121 ? 1 : 0));
    float a0 = 0.f, a1 = 0.f;
    for (int kb = 0; kb < deg; kb += 64) {
        int cn = min(64, deg - kb);
        __syncthreads();
        if (tid < cn) s_src[tid] = col[r0 + kb + tid];
        for (int idx = tid; idx < cn * 4; idx += 256)
            s_al[idx >> 2][idx & 3] = alphaE[(size_t)(r0 + kb) * 4 + idx];
        __syncthreads();
        if (act) {
#pragma unroll 4
            for (int kk = 0; kk < cn; kk++) {
                u32 v = *(const u32*)&xh[(size_t)s_src[kk] * HC3 + c0];
                a0 += s_al[kk][h0] * bf2f((u16)(v & 0xffff));
                a1 += s_al[kk][h1] * bf2f((u16)(v >> 16));
            }
        }
    }
    if (act) { s_out[c0] = a0; s_out[c1] = a1; }
    __syncthreads();
    if (tid < NCLS) {
        float o = 0.25f * (s_out[tid] + s_out[NCLS + tid] + s_out[2 * NCLS + tid] + s_out[3 * NCLS + tid])
                  + b3[tid] + lin3[(size_t)n * NCLS + tid];
        out[(size_t)n * NCLS + tid] = o;
    }
}

extern "C" void kernel_launch(void* const* d_in, const int* in_sizes, int n_in,
                              void* d_out, int out_size, void* d_ws, size_t ws_size,
                              hipStream_t stream) {
    const float* x   = (const float*)d_in[0];
    const int*   ei  = (const int*)d_in[1];
    const float* W1  = (const float*)d_in[2];
    const float* a1s = (const float*)d_in[3];
    const float* a1d = (const float*)d_in[4];
    const float* b1  = (const float*)d_in[5];
    const float* l1W = (const float*)d_in[6];
    const float* l1b = (const float*)d_in[7];
    const float* W2  = (const float*)d_in[8];
    const float* a2s = (const float*)d_in[9];
    const float* a2d = (const float*)d_in[10];
    const float* b2  = (const float*)d_in[11];
    const float* W3  = (const float*)d_in[12];
    const float* a3s = (const float*)d_in[13];
    const float* a3d = (const float*)d_in[14];
    const float* b3  = (const float*)d_in[15];
    const float* l3W = (const float*)d_in[16];
    const float* l3b = (const float*)d_in[17];

    const int N = in_sizes[0] / F_IN;   // 50000
    const int E = in_sizes[1] / 2;      // 400000
    const int* srcv = ei;
    const int* dstv = ei + E;

    char* ws = (char*)d_ws;
    size_t off = 0;
    auto alloc = [&](size_t bytes) -> char* {
        char* p = ws + off;
        off += (bytes + 255) & ~(size_t)255;
        return p;
    };
    u16*   xh   = (u16*)alloc((size_t)N * HC3 * 2);      // GEMM bf16 outputs
    float* h1   = (float*)alloc((size_t)N * HC12 * 4);   // fp32 (residual for layer 2)
    u16*   h1b  = (u16*)alloc((size_t)N * HC12 * 2);     // bf16 A for layer-2 GEMM
    u16*   h2b  = (u16*)alloc((size_t)N * HC12 * 2);     // bf16 A for layer-3 GEMM
    u16*   xb   = (u16*)alloc((size_t)N * F_IN * 2);     // bf16 x for layer-1 GEMM
    float* lin  = (float*)alloc((size_t)N * NCLS * 4);
    float* as_  = (float*)alloc((size_t)N * 4 * 4);
    float* ad_  = (float*)alloc((size_t)N * 4 * 4);
    int* rowp   = (int*)alloc((size_t)(N + 1) * 4);
    int* degc   = (int*)alloc((size_t)N * 4);
    int* cur    = (int*)alloc((size_t)N * 4);
    int* col    = (int*)alloc((size_t)E * 4);
    float* alphaE = (float*)alloc((size_t)E * 4 * 4);
    u16* C1h = (u16*)alloc((size_t)512 * 128 * 2);
    u16* C2h = (u16*)alloc((size_t)256 * 256 * 2);
    u16* C3h = (u16*)alloc((size_t)605 * 256 * 2);
    (void)ws_size; (void)n_in; (void)out_size;

    // ---- CSR build ----
    hipMemsetAsync(degc, 0, (size_t)N * 4, stream);
    hipMemsetAsync(cur, 0, (size_t)N * 4, stream);
    hist_kernel<<<(E + 255) / 256, 256, 0, stream>>>(dstv, degc, E);
    scan_kernel<<<1, 1024, 0, stream>>>(degc, rowp, N);
    scatter_kernel<<<(E + 255) / 256, 256, 0, stream>>>(srcv, dstv, rowp, cur, col, E);

    // ---- weight transpose/round + x convert ----
    splitT_all_kernel<<<(285952 + 255) / 256, 256, 0, stream>>>(W1, l1W, W2, W3, l3W,
                                                                C1h, C2h, C3h);
    cvt_bf16_kernel<<<(N * F_IN / 2 + 255) / 256, 256, 0, stream>>>(x, (u32*)xb, N * F_IN / 2);

    int ny = (N + BM - 1) / BM;
    int sgrid = (N * 4 + 255) / 256;

    // ---- layer 1: N=512 (cols 0-255 -> xh bf16, 256-511 -> h1 fp32 + l1b) ----
    gemm_bf16<<<4 * ny, 256, 0, stream>>>(xb, C1h, N, F_IN, 512, 4, ny,
                                          256, xh, 256, h1, l1b, 256);
    alpha_kernel<<<N, 256, 0, stream>>>(xh, a1s, a1d, as_, ad_, 64);
    stats_alpha_kernel<<<sgrid, 256, 0, stream>>>(rowp, col, as_, ad_, alphaE, N);
    agg_kernel_256<<<N, 256, 0, stream>>>(xh, rowp, col, alphaE, b1, h1, h1, h1b);

    // ---- layer 2: N=256, out h2 bf16 only ----
    gemm_bf16<<<2 * ny, 256, 0, stream>>>(h1b, C2h, N, HC12, 256, 2, ny,
                                          256, xh, 256, nullptr, nullptr, 0);
    alpha_kernel<<<N, 256, 0, stream>>>(xh, a2s, a2d, as_, ad_, 64);
    stats_alpha_kernel<<<sgrid, 256, 0, stream>>>(rowp, col, as_, ad_, alphaE, N);
    agg_kernel_256<<<N, 256, 0, stream>>>(xh, rowp, col, alphaE, b2, h1, nullptr, h2b);

    // ---- layer 3: N=605 (cols 0-483 -> xh bf16, 484-604 -> lin fp32 + l3b) ----
    gemm_bf16<<<5 * ny, 256, 0, stream>>>(h2b, C3h, N, HC12, 605, 5, ny,
                                          484, xh, 484, lin, l3b, NCLS);
    alpha_kernel<<<N, 256, 0, stream>>>(xh, a3s, a3d, as_, ad_, NCLS);
    stats_alpha_kernel<<<sgrid, 256, 0, stream>>>(rowp, col, as_, ad_, alphaE, N);
    agg_out_kernel<<<N, 256, 0, stream>>>(xh, rowp, col, alphaE, b3, lin, (float*)d_out);
}

// Round 12
// 786.630 us; speedup vs baseline: 1.0123x; 1.0123x over previous
//
#include <hip/hip_runtime.h>
#include <hip/hip_bf16.h>
#include <cstdint>
#include <cstddef>

#define F_IN 128
#define HC12 256   // HEADS*HID for layers 1/2
#define HC3 484    // OUT_HEADS*N_CLS for layer 3
#define NCLS 121

typedef unsigned short u16;
typedef unsigned int u32;
typedef __attribute__((ext_vector_type(8))) short short8;
typedef __attribute__((ext_vector_type(4))) float float4v;

static __device__ __forceinline__ float lrelu(float x) { return x > 0.f ? x : 0.2f * x; }

static __device__ __forceinline__ u16 f2bf(float f) {
    union { float f; unsigned u; } v; v.f = f;
    unsigned r = v.u + 0x7FFF + ((v.u >> 16) & 1);
    return (u16)(r >> 16);
}
static __device__ __forceinline__ float bf2f(u16 h) {
    union { unsigned u; float f; } v; v.u = ((unsigned)h) << 16;
    return v.f;
}
static __device__ __forceinline__ u32 pk_bf16(float a, float b) {
    float2 f; f.x = a; f.y = b;
    union { __hip_bfloat162 b2; u32 u; } cv;
    cv.b2 = __float22bfloat162_rn(f);
    return cv.u;
}

// ---------------- CSR build ----------------
__global__ void hist_kernel(const int* __restrict__ dst, int* __restrict__ deg, int E) {
    int e = blockIdx.x * 256 + threadIdx.x;
    if (e < E) atomicAdd(&deg[dst[e]], 1);
}

__global__ __launch_bounds__(1024) void scan_kernel(const int* __restrict__ deg,
                                                    int* __restrict__ rowp, int N) {
    __shared__ int swave[16];
    __shared__ int s_carry;
    int tid = threadIdx.x;
    int w = tid >> 6, lane = tid & 63;
    if (tid == 0) { rowp[0] = 0; s_carry = 0; }
    __syncthreads();
    for (int base = 0; base < N; base += 4096) {
        int i0 = base + tid * 4;
        int v0 = (i0     < N) ? deg[i0]     : 0;
        int v1 = (i0 + 1 < N) ? deg[i0 + 1] : 0;
        int v2 = (i0 + 2 < N) ? deg[i0 + 2] : 0;
        int v3 = (i0 + 3 < N) ? deg[i0 + 3] : 0;
        int t = v0 + v1 + v2 + v3;
        int sc = t;
#pragma unroll
        for (int off = 1; off < 64; off <<= 1) {
            int u = __shfl_up(sc, off, 64);
            if (lane >= off) sc += u;
        }
        if (lane == 63) swave[w] = sc;
        __syncthreads();
        if (w == 0) {
            int ws = (lane < 16) ? swave[lane] : 0;
#pragma unroll
            for (int off = 1; off < 16; off <<= 1) {
                int u = __shfl_up(ws, off, 64);
                if (lane >= off) ws += u;
            }
            if (lane < 16) swave[lane] = ws;
        }
        __syncthreads();
        int carry = s_carry;
        int tb = carry + ((w > 0) ? swave[w - 1] : 0) + sc - t;
        if (i0     < N) rowp[i0 + 1] = tb + v0;
        if (i0 + 1 < N) rowp[i0 + 2] = tb + v0 + v1;
        if (i0 + 2 < N) rowp[i0 + 3] = tb + v0 + v1 + v2;
        if (i0 + 3 < N) rowp[i0 + 4] = tb + t;
        __syncthreads();
        if (tid == 1023) s_carry = carry + swave[15];
        __syncthreads();
    }
}

__global__ void scatter_kernel(const int* __restrict__ src, const int* __restrict__ dst,
                               const int* __restrict__ rowp, int* __restrict__ cur,
                               int* __restrict__ col, int E) {
    int e = blockIdx.x * 256 + threadIdx.x;
    if (e < E) {
        int d = dst[e];
        int pos = rowp[d] + atomicAdd(&cur[d], 1);
        col[pos] = src[e];
    }
}

// ---------------- fused weight transpose -> bf16 ----------------
__global__ void splitT_all_kernel(const float* W1, const float* l1W, const float* W2,
                                  const float* W3, const float* l3W,
                                  u16* C1h, u16* C2h, u16* C3h) {
    int i = blockIdx.x * 256 + threadIdx.x;
    const float* B; u16* hi; int K, N;
    if (i < 32768)       { B = W1;  hi = C1h;             K = 128; N = 256; }
    else if (i < 65536)  { B = l1W; hi = C1h + 256 * 128; K = 128; N = 256; i -= 32768; }
    else if (i < 131072) { B = W2;  hi = C2h;             K = 256; N = 256; i -= 65536; }
    else if (i < 254976) { B = W3;  hi = C3h;             K = 256; N = 484; i -= 131072; }
    else if (i < 285952) { B = l3W; hi = C3h + 484 * 256; K = 256; N = 121; i -= 254976; }
    else return;
    int n = i % N, k = i / N;
    hi[(size_t)n * K + k] = f2bf(B[(size_t)k * N + n]);
}

// ---------------- fp32 -> bf16 convert (x) ----------------
__global__ void cvt_bf16_kernel(const float* __restrict__ in, u32* __restrict__ out, int npairs) {
    int i = blockIdx.x * 256 + threadIdx.x;
    if (i < npairs) {
        float2 f = *(const float2*)&in[2 * i];
        out[i] = pk_bf16(f.x, f.y);
    }
}

// ---------------- pure-bf16 MFMA GEMM, 128x128 tile, occupancy-capped ----------------
// A: bf16 [M][K]; BT: bf16 [Ntot][K]. Staging = pure uint4 copies.
// LDS padded to 56 KB => hard cap of 2 blocks/CU. Evidence (R7-R11): HBM write
// amplification of the 2-B bf16 C-stores scales with resident blocks/CU
// (2->1.1x, 3->1.9x, 4->3.8x) -- concurrent dirty footprint vs 4 MB L2/XCD.
#define BM 128
#define BN 128
#define BK 32
#define LDA 40
#define SMEM_U16 28672   // 57344 B total LDS -> floor(160/56) = 2 blocks/CU

__global__ __launch_bounds__(256, 2) void gemm_bf16(const u16* __restrict__ A,
                                                    const u16* __restrict__ BT,
                                                    int M, int K, int Ntot,
                                                    int nx, int ny,
                                                    int Nb, u16* __restrict__ Cb, int strideB,
                                                    float* __restrict__ Cf,
                                                    const float* __restrict__ biasf, int strideF) {
    __shared__ __align__(16) u16 smem[SMEM_U16];
    u16* sA = smem;
    u16* sB = smem + BM * LDA;
    int tid = threadIdx.x;
    int wave = tid >> 6, lane = tid & 63;
    int wr = wave >> 1, wc = wave & 1;

    // XCD-aware block swizzle: col-blocks of one row-tile land 8 apart (same XCD)
    int bid = blockIdx.x;
    int G = nx * 8;
    int g = bid / G;
    int rem = ny - g * 8;
    int rb, cb;
    if (rem >= 8) {
        int r = bid - g * G;
        rb = g * 8 + (r & 7);
        cb = r >> 3;
    } else {
        int t = bid - g * G;
        rb = g * 8 + t % rem;
        cb = t / rem;
    }
    int m0 = rb * BM, n0 = cb * BN;

    int fm = lane & 15;
    int q = lane >> 4;
    int r0 = tid >> 2;
    int c0 = (tid & 3) * 8;

    float4v acc[4][4];
#pragma unroll
    for (int i = 0; i < 4; i++)
#pragma unroll
        for (int j = 0; j < 4; j++) acc[i][j] = (float4v){0.f, 0.f, 0.f, 0.f};

    const uint4 zero4 = {0u, 0u, 0u, 0u};
    uint4 pa[2], pb[2];

#pragma unroll
    for (int j = 0; j < 2; j++) {
        int gr = m0 + r0 + j * 64;
        pa[j] = (gr < M) ? *(const uint4*)&A[(size_t)gr * K + c0] : zero4;
        int gn = n0 + r0 + j * 64;
        pb[j] = (gn < Ntot) ? *(const uint4*)&BT[(size_t)gn * K + c0] : zero4;
    }

    for (int kc = 0; kc < K; kc += BK) {
#pragma unroll
        for (int j = 0; j < 2; j++) {
            int row = r0 + j * 64;
            *(uint4*)&sA[row * LDA + c0] = pa[j];
            *(uint4*)&sB[row * LDA + c0] = pb[j];
        }
        __syncthreads();

        int kn = kc + BK;
        if (kn < K) {
#pragma unroll
            for (int j = 0; j < 2; j++) {
                int gr = m0 + r0 + j * 64;
                pa[j] = (gr < M) ? *(const uint4*)&A[(size_t)gr * K + kn + c0] : zero4;
                int gn = n0 + r0 + j * 64;
                pb[j] = (gn < Ntot) ? *(const uint4*)&BT[(size_t)gn * K + kn + c0] : zero4;
            }
        }

        short8 ah[4];
#pragma unroll
        for (int mi = 0; mi < 4; mi++) {
            int row = wr * 64 + mi * 16 + fm;
            ah[mi] = *(const short8*)&sA[row * LDA + q * 8];
        }
#pragma unroll
        for (int ni = 0; ni < 4; ni++) {
            int nn = wc * 64 + ni * 16 + fm;
            short8 bh = *(const short8*)&sB[nn * LDA + q * 8];
#pragma unroll
            for (int mi = 0; mi < 4; mi++)
                acc[mi][ni] = __builtin_amdgcn_mfma_f32_16x16x32_bf16(ah[mi], bh, acc[mi][ni], 0, 0, 0);
        }
        __syncthreads();
    }

    // direct epilogue (2-B bf16 stores are fine at 2 blocks/CU: write-amp ~1.1x)
#pragma unroll
    for (int mi = 0; mi < 4; mi++) {
#pragma unroll
        for (int ni = 0; ni < 4; ni++) {
            int colg = n0 + wc * 64 + ni * 16 + fm;
            if (colg >= Ntot) continue;
#pragma unroll
            for (int r = 0; r < 4; r++) {
                int rowg = m0 + wr * 64 + mi * 16 + q * 4 + r;
                if (rowg >= M) continue;
                float v = acc[mi][ni][r];
                if (colg < Nb) {
                    Cb[(size_t)rowg * strideB + colg] = f2bf(v);
                } else {
                    int cf = colg - Nb;
                    Cf[(size_t)rowg * strideF + cf] = v + biasf[cf];
                }
            }
        }
    }
}

// ---------------- per-node attention coefficients (bf16 xh) ----------------
__global__ __launch_bounds__(256) void alpha_kernel(const u16* __restrict__ xh,
                                                    const float* __restrict__ a_s,
                                                    const float* __restrict__ a_d,
                                                    float* __restrict__ as_o,
                                                    float* __restrict__ ad_o, int C) {
    int n = blockIdx.x;
    int w = threadIdx.x >> 6, lane = threadIdx.x & 63;
    const u16* row = xh + (size_t)n * 4 * C + (size_t)w * C;
    float ss = 0.f, sd = 0.f;
    for (int c = lane; c < C; c += 64) {
        float v = bf2f(row[c]);
        ss += v * a_s[w * C + c];
        sd += v * a_d[w * C + c];
    }
    for (int o = 32; o; o >>= 1) {
        ss += __shfl_xor(ss, o, 64);
        sd += __shfl_xor(sd, o, 64);
    }
    if (!lane) {
        as_o[n * 4 + w] = ss;
        ad_o[n * 4 + w] = sd;
    }
}

// ---------------- fused softmax stats + per-edge alpha ----------------
__global__ __launch_bounds__(256) void stats_alpha_kernel(const int* __restrict__ rowp,
                                                          const int* __restrict__ col,
                                                          const float* __restrict__ asrc,
                                                          const float* __restrict__ adst,
                                                          float* __restrict__ alphaE, int N) {
    int i = blockIdx.x * 256 + threadIdx.x;
    if (i >= N * 4) return;
    int n = i >> 2, h = i & 3;
    int r0 = rowp[n], r1 = rowp[n + 1];
    float ad = adst[i];
    float m = -3.4e38f, s = 0.f;
    for (int e = r0; e < r1; e++) {
        int sc = col[e];
        float l = lrelu(asrc[sc * 4 + h] + ad);
        float nm = fmaxf(m, l);
        s = s * __expf(m - nm) + __expf(l - nm);
        m = nm;
    }
    float rd = 1.f / (s + 1e-16f);
    for (int e = r0; e < r1; e++) {
        int sc = col[e];
        float l = lrelu(asrc[sc * 4 + h] + ad);
        alphaE[(size_t)e * 4 + h] = __expf(l - m) * rd;
    }
}

// ---------------- gather+FMA aggregate, HC=256 (layers 1/2) ----------------
// out (fp32) and outb (bf16) are each optional. res/out may alias.
__global__ __launch_bounds__(256) void agg_kernel_256(const u16* __restrict__ xh,
                                                      const int* __restrict__ rowp,
                                                      const int* __restrict__ col,
                                                      const float* __restrict__ alphaE,
                                                      const float* __restrict__ bias,
                                                      const float* res,
                                                      float* out, u16* outb) {
    int n = blockIdx.x, tid = threadIdx.x;
    int r0 = rowp[n], deg = rowp[n + 1] - r0;
    __shared__ int s_src[64];
    __shared__ float s_al[64][4];
    __shared__ float s_part[4][HC12];
    int g = tid >> 6;
    int sub = tid & 63;
    int c = sub * 4;
    int h = sub >> 4;
    float a0 = 0.f, a1 = 0.f, a2 = 0.f, a3 = 0.f;
    for (int kb = 0; kb < deg; kb += 64) {
        int cn = min(64, deg - kb);
        __syncthreads();
        if (tid < cn) s_src[tid] = col[r0 + kb + tid];
        for (int idx = tid; idx < cn * 4; idx += 256)
            s_al[idx >> 2][idx & 3] = alphaE[(size_t)(r0 + kb) * 4 + idx];
        __syncthreads();
#pragma unroll 4
        for (int kk = g; kk < cn; kk += 4) {
            uint2 v = *(const uint2*)&xh[(size_t)s_src[kk] * HC12 + c];
            float al = s_al[kk][h];
            a0 += al * bf2f((u16)(v.x & 0xffff));
            a1 += al * bf2f((u16)(v.x >> 16));
            a2 += al * bf2f((u16)(v.y & 0xffff));
            a3 += al * bf2f((u16)(v.y >> 16));
        }
    }
    s_part[g][c] = a0; s_part[g][c + 1] = a1; s_part[g][c + 2] = a2; s_part[g][c + 3] = a3;
    __syncthreads();
    float v = s_part[0][tid] + s_part[1][tid] + s_part[2][tid] + s_part[3][tid]
              + bias[tid] + res[(size_t)n * HC12 + tid];
    float o = v > 0.f ? v : expm1f(v);
    if (out)  out[(size_t)n * HC12 + tid] = o;
    if (outb) outb[(size_t)n * HC12 + tid] = f2bf(o);
}

// ---------------- layer 3 gather: HC=484, mean heads + b3 + lin3 -> d_out ----------------
__global__ __launch_bounds__(256) void agg_out_kernel(const u16* __restrict__ xh,
                                                      const int* __restrict__ rowp,
                                                      const int* __restrict__ col,
                                                      const float* __restrict__ alphaE,
                                                      const float* __restrict__ b3,
                                                      const float* __restrict__ lin3,
                                                      float* __restrict__ out) {
    int n = blockIdx.x, tid = threadIdx.x;
    int r0 = rowp[n], deg = rowp[n + 1] - r0;
    __shared__ int s_src[64];
    __shared__ float s_al[64][4];
    __shared__ float s_out[HC3];
    bool act = tid < 242;
    int c0 = 2 * tid, c1 = c0 + 1;
    int h0 = c0 >= 363 ? 3 : (c0 >= 242 ? 2 : (c0 >= 121 ? 1 : 0));
    int h1 = c1 >= 363 ? 3 : (c1 >= 242 ? 2 : (c1 >= 121 ? 1 : 0));
    float a0 = 0.f, a1 = 0.f;
    for (int kb = 0; kb < deg; kb += 64) {
        int cn = min(64, deg - kb);
        __syncthreads();
        if (tid < cn) s_src[tid] = col[r0 + kb + tid];
        for (int idx = tid; idx < cn * 4; idx += 256)
            s_al[idx >> 2][idx & 3] = alphaE[(size_t)(r0 + kb) * 4 + idx];
        __syncthreads();
        if (act) {
#pragma unroll 4
            for (int kk = 0; kk < cn; kk++) {
                u32 v = *(const u32*)&xh[(size_t)s_src[kk] * HC3 + c0];
                a0 += s_al[kk][h0] * bf2f((u16)(v & 0xffff));
                a1 += s_al[kk][h1] * bf2f((u16)(v >> 16));
            }
        }
    }
    if (act) { s_out[c0] = a0; s_out[c1] = a1; }
    __syncthreads();
    if (tid < NCLS) {
        float o = 0.25f * (s_out[tid] + s_out[NCLS + tid] + s_out[2 * NCLS + tid] + s_out[3 * NCLS + tid])
                  + b3[tid] + lin3[(size_t)n * NCLS + tid];
        out[(size_t)n * NCLS + tid] = o;
    }
}

extern "C" void kernel_launch(void* const* d_in, const int* in_sizes, int n_in,
                              void* d_out, int out_size, void* d_ws, size_t ws_size,
                              hipStream_t stream) {
    const float* x   = (const float*)d_in[0];
    const int*   ei  = (const int*)d_in[1];
    const float* W1  = (const float*)d_in[2];
    const float* a1s = (const float*)d_in[3];
    const float* a1d = (const float*)d_in[4];
    const float* b1  = (const float*)d_in[5];
    const float* l1W = (const float*)d_in[6];
    const float* l1b = (const float*)d_in[7];
    const float* W2  = (const float*)d_in[8];
    const float* a2s = (const float*)d_in[9];
    const float* a2d = (const float*)d_in[10];
    const float* b2  = (const float*)d_in[11];
    const float* W3  = (const float*)d_in[12];
    const float* a3s = (const float*)d_in[13];
    const float* a3d = (const float*)d_in[14];
    const float* b3  = (const float*)d_in[15];
    const float* l3W = (const float*)d_in[16];
    const float* l3b = (const float*)d_in[17];

    const int N = in_sizes[0] / F_IN;   // 50000
    const int E = in_sizes[1] / 2;      // 400000
    const int* srcv = ei;
    const int* dstv = ei + E;

    char* ws = (char*)d_ws;
    size_t off = 0;
    auto alloc = [&](size_t bytes) -> char* {
        char* p = ws + off;
        off += (bytes + 255) & ~(size_t)255;
        return p;
    };
    u16*   xh   = (u16*)alloc((size_t)N * HC3 * 2);      // GEMM bf16 outputs
    float* h1   = (float*)alloc((size_t)N * HC12 * 4);   // fp32 (residual for layer 2)
    u16*   h1b  = (u16*)alloc((size_t)N * HC12 * 2);     // bf16 A for layer-2 GEMM
    u16*   h2b  = (u16*)alloc((size_t)N * HC12 * 2);     // bf16 A for layer-3 GEMM
    u16*   xb   = (u16*)alloc((size_t)N * F_IN * 2);     // bf16 x for layer-1 GEMM
    float* lin  = (float*)alloc((size_t)N * NCLS * 4);
    float* as_  = (float*)alloc((size_t)N * 4 * 4);
    float* ad_  = (float*)alloc((size_t)N * 4 * 4);
    int* rowp   = (int*)alloc((size_t)(N + 1) * 4);
    int* degc   = (int*)alloc((size_t)N * 4);
    int* cur    = (int*)alloc((size_t)N * 4);
    int* col    = (int*)alloc((size_t)E * 4);
    float* alphaE = (float*)alloc((size_t)E * 4 * 4);
    u16* C1h = (u16*)alloc((size_t)512 * 128 * 2);
    u16* C2h = (u16*)alloc((size_t)256 * 256 * 2);
    u16* C3h = (u16*)alloc((size_t)605 * 256 * 2);
    (void)ws_size; (void)n_in; (void)out_size;

    // ---- CSR build ----
    hipMemsetAsync(degc, 0, (size_t)N * 4, stream);
    hipMemsetAsync(cur, 0, (size_t)N * 4, stream);
    hist_kernel<<<(E + 255) / 256, 256, 0, stream>>>(dstv, degc, E);
    scan_kernel<<<1, 1024, 0, stream>>>(degc, rowp, N);
    scatter_kernel<<<(E + 255) / 256, 256, 0, stream>>>(srcv, dstv, rowp, cur, col, E);

    // ---- weight transpose/round + x convert ----
    splitT_all_kernel<<<(285952 + 255) / 256, 256, 0, stream>>>(W1, l1W, W2, W3, l3W,
                                                                C1h, C2h, C3h);
    cvt_bf16_kernel<<<(N * F_IN / 2 + 255) / 256, 256, 0, stream>>>(x, (u32*)xb, N * F_IN / 2);

    int ny = (N + BM - 1) / BM;
    int sgrid = (N * 4 + 255) / 256;

    // ---- layer 1: N=512 (cols 0-255 -> xh bf16, 256-511 -> h1 fp32 + l1b) ----
    gemm_bf16<<<4 * ny, 256, 0, stream>>>(xb, C1h, N, F_IN, 512, 4, ny,
                                          256, xh, 256, h1, l1b, 256);
    alpha_kernel<<<N, 256, 0, stream>>>(xh, a1s, a1d, as_, ad_, 64);
    stats_alpha_kernel<<<sgrid, 256, 0, stream>>>(rowp, col, as_, ad_, alphaE, N);
    agg_kernel_256<<<N, 256, 0, stream>>>(xh, rowp, col, alphaE, b1, h1, h1, h1b);

    // ---- layer 2: N=256, out h2 bf16 only ----
    gemm_bf16<<<2 * ny, 256, 0, stream>>>(h1b, C2h, N, HC12, 256, 2, ny,
                                          256, xh, 256, nullptr, nullptr, 0);
    alpha_kernel<<<N, 256, 0, stream>>>(xh, a2s, a2d, as_, ad_, 64);
    stats_alpha_kernel<<<sgrid, 256, 0, stream>>>(rowp, col, as_, ad_, alphaE, N);
    agg_kernel_256<<<N, 256, 0, stream>>>(xh, rowp, col, alphaE, b2, h1, nullptr, h2b);

    // ---- layer 3: N=605 (cols 0-483 -> xh bf16, 484-604 -> lin fp32 + l3b) ----
    gemm_bf16<<<5 * ny, 256, 0, stream>>>(h2b, C3h, N, HC12, 605, 5, ny,
                                          484, xh, 484, lin, l3b, NCLS);
    alpha_kernel<<<N, 256, 0, stream>>>(xh, a3s, a3d, as_, ad_, NCLS);
    stats_alpha_kernel<<<sgrid, 256, 0, stream>>>(rowp, col, as_, ad_, alphaE, N);
    agg_out_kernel<<<N, 256, 0, stream>>>(xh, rowp, col, alphaE, b3, lin, (float*)d_out);
}

// Round 13
// 722.704 us; speedup vs baseline: 1.1018x; 1.0885x over previous
//
#include <hip/hip_runtime.h>
#include <hip/hip_bf16.h>
#include <cstdint>
#include <cstddef>

#define F_IN 128
#define HC12 256   // HEADS*HID for layers 1/2
#define HC3 484    // OUT_HEADS*N_CLS for layer 3
#define NCLS 121

typedef unsigned short u16;
typedef unsigned int u32;
typedef __attribute__((ext_vector_type(8))) short short8;
typedef __attribute__((ext_vector_type(4))) float float4v;

static __device__ __forceinline__ float lrelu(float x) { return x > 0.f ? x : 0.2f * x; }

static __device__ __forceinline__ u16 f2bf(float f) {
    union { float f; unsigned u; } v; v.f = f;
    unsigned r = v.u + 0x7FFF + ((v.u >> 16) & 1);
    return (u16)(r >> 16);
}
static __device__ __forceinline__ float bf2f(u16 h) {
    union { unsigned u; float f; } v; v.u = ((unsigned)h) << 16;
    return v.f;
}
static __device__ __forceinline__ u32 pk_bf16(float a, float b) {
    float2 f; f.x = a; f.y = b;
    union { __hip_bfloat162 b2; u32 u; } cv;
    cv.b2 = __float22bfloat162_rn(f);
    return cv.u;
}

// ---------------- CSR build ----------------
__global__ void hist_kernel(const int* __restrict__ dst, int* __restrict__ deg, int E) {
    int e = blockIdx.x * 256 + threadIdx.x;
    if (e < E) atomicAdd(&deg[dst[e]], 1);
}

__global__ __launch_bounds__(1024) void scan_kernel(const int* __restrict__ deg,
                                                    int* __restrict__ rowp, int N) {
    __shared__ int swave[16];
    __shared__ int s_carry;
    int tid = threadIdx.x;
    int w = tid >> 6, lane = tid & 63;
    if (tid == 0) { rowp[0] = 0; s_carry = 0; }
    __syncthreads();
    for (int base = 0; base < N; base += 4096) {
        int i0 = base + tid * 4;
        int v0 = (i0     < N) ? deg[i0]     : 0;
        int v1 = (i0 + 1 < N) ? deg[i0 + 1] : 0;
        int v2 = (i0 + 2 < N) ? deg[i0 + 2] : 0;
        int v3 = (i0 + 3 < N) ? deg[i0 + 3] : 0;
        int t = v0 + v1 + v2 + v3;
        int sc = t;
#pragma unroll
        for (int off = 1; off < 64; off <<= 1) {
            int u = __shfl_up(sc, off, 64);
            if (lane >= off) sc += u;
        }
        if (lane == 63) swave[w] = sc;
        __syncthreads();
        if (w == 0) {
            int ws = (lane < 16) ? swave[lane] : 0;
#pragma unroll
            for (int off = 1; off < 16; off <<= 1) {
                int u = __shfl_up(ws, off, 64);
                if (lane >= off) ws += u;
            }
            if (lane < 16) swave[lane] = ws;
        }
        __syncthreads();
        int carry = s_carry;
        int tb = carry + ((w > 0) ? swave[w - 1] : 0) + sc - t;
        if (i0     < N) rowp[i0 + 1] = tb + v0;
        if (i0 + 1 < N) rowp[i0 + 2] = tb + v0 + v1;
        if (i0 + 2 < N) rowp[i0 + 3] = tb + v0 + v1 + v2;
        if (i0 + 3 < N) rowp[i0 + 4] = tb + t;
        __syncthreads();
        if (tid == 1023) s_carry = carry + swave[15];
        __syncthreads();
    }
}

__global__ void scatter_kernel(const int* __restrict__ src, const int* __restrict__ dst,
                               const int* __restrict__ rowp, int* __restrict__ cur,
                               int* __restrict__ col, int E) {
    int e = blockIdx.x * 256 + threadIdx.x;
    if (e < E) {
        int d = dst[e];
        int pos = rowp[d] + atomicAdd(&cur[d], 1);
        col[pos] = src[e];
    }
}

// ---------------- fused weight transpose -> plain bf16 ----------------
__global__ void splitT_all_kernel(const float* W1, const float* l1W, const float* W2,
                                  const float* W3, const float* l3W,
                                  u16* C1h, u16* C2h, u16* C3h) {
    int i = blockIdx.x * 256 + threadIdx.x;
    const float* B; u16* hi; int K, N;
    if (i < 32768)       { B = W1;  hi = C1h;             K = 128; N = 256; }
    else if (i < 65536)  { B = l1W; hi = C1h + 256 * 128; K = 128; N = 256; i -= 32768; }
    else if (i < 131072) { B = W2;  hi = C2h;             K = 256; N = 256; i -= 65536; }
    else if (i < 254976) { B = W3;  hi = C3h;             K = 256; N = 484; i -= 131072; }
    else if (i < 285952) { B = l3W; hi = C3h + 484 * 256; K = 256; N = 121; i -= 254976; }
    else return;
    int n = i % N, k = i / N;
    hi[(size_t)n * K + k] = f2bf(B[(size_t)k * N + n]);
}

// ---------------- MFMA GEMM: A fp32 (hi/lo split in-reg) x B bf16 ----------------
// R8 configuration — best measured (93 us L3 GEMM, total 722 us).
// HW law (R7-R12): bf16 2-B C-store write amplification scales with resident
// blocks/CU (2->1.0x, 3->1.9x, 4->3.8x): concurrent dirty-line footprint vs
// 4 MB L2/XCD. This config (30 KB LDS + (256,3)) measured NO amplification.
// GEMM plateau ~93-104 us is structural: 2-barrier K-loop drains vmcnt at each
// barrier (m97 class); staging-side tweaks (R9-R12) do not move it.
#define BM 128
#define BN 128
#define BK 32
#define LDA 40

__global__ __launch_bounds__(256, 3) void gemm_mfma_split(const float* __restrict__ A,
                                                          const u16* __restrict__ BThi,
                                                          int M, int K, int Ntot,
                                                          int nx, int ny,
                                                          int Nb, u16* __restrict__ Cb, int strideB,
                                                          float* __restrict__ Cf,
                                                          const float* __restrict__ biasf, int strideF) {
    __shared__ __align__(16) u16 sAh[BM * LDA];
    __shared__ __align__(16) u16 sAl[BM * LDA];
    __shared__ __align__(16) u16 sBh[BN * LDA];
    int tid = threadIdx.x;
    int wave = tid >> 6, lane = tid & 63;
    int wr = wave >> 1, wc = wave & 1;

    // XCD-aware swizzle: col-blocks of one row-tile land 8 apart (same XCD L2)
    int bid = blockIdx.x;
    int G = nx * 8;
    int g = bid / G;
    int rem = ny - g * 8;
    int rb, cb;
    if (rem >= 8) {
        int r = bid - g * G;
        rb = g * 8 + (r & 7);
        cb = r >> 3;
    } else {
        int t = bid - g * G;
        rb = g * 8 + t % rem;
        cb = t / rem;
    }
    int m0 = rb * BM, n0 = cb * BN;

    int fm = lane & 15;
    int q = lane >> 4;
    int r0 = tid >> 2;
    int c0 = (tid & 3) * 8;

    float4v acc[4][4];
#pragma unroll
    for (int i = 0; i < 4; i++)
#pragma unroll
        for (int j = 0; j < 4; j++) acc[i][j] = (float4v){0.f, 0.f, 0.f, 0.f};

    const uint4 zero4 = {0u, 0u, 0u, 0u};
    const float4 zf4 = {0.f, 0.f, 0.f, 0.f};

    float4 pa[2][2];
    uint4 pbh[2];

#pragma unroll
    for (int j = 0; j < 2; j++) {
        int gr = m0 + r0 + j * 64;
        if (gr < M) {
            pa[j][0] = *(const float4*)&A[(size_t)gr * K + c0];
            pa[j][1] = *(const float4*)&A[(size_t)gr * K + c0 + 4];
        } else { pa[j][0] = zf4; pa[j][1] = zf4; }
        int gn = n0 + r0 + j * 64;
        pbh[j] = (gn < Ntot) ? *(const uint4*)&BThi[(size_t)gn * K + c0] : zero4;
    }

    for (int kc = 0; kc < K; kc += BK) {
#pragma unroll
        for (int j = 0; j < 2; j++) {
            float va[8];
            va[0] = pa[j][0].x; va[1] = pa[j][0].y; va[2] = pa[j][0].z; va[3] = pa[j][0].w;
            va[4] = pa[j][1].x; va[5] = pa[j][1].y; va[6] = pa[j][1].z; va[7] = pa[j][1].w;
            uint4 vh, vl;
#pragma unroll
            for (int t = 0; t < 4; t++) {
                u32 hu = pk_bf16(va[2 * t], va[2 * t + 1]);
                float l0 = va[2 * t]     - bf2f((u16)(hu & 0xffff));
                float l1 = va[2 * t + 1] - bf2f((u16)(hu >> 16));
                ((u32*)&vh)[t] = hu;
                ((u32*)&vl)[t] = pk_bf16(l0, l1);
            }
            int row = r0 + j * 64;
            *(uint4*)&sAh[row * LDA + c0] = vh;
            *(uint4*)&sAl[row * LDA + c0] = vl;
            *(uint4*)&sBh[row * LDA + c0] = pbh[j];
        }
        __syncthreads();

        int kn = kc + BK;
        if (kn < K) {
#pragma unroll
            for (int j = 0; j < 2; j++) {
                int gr = m0 + r0 + j * 64;
                if (gr < M) {
                    pa[j][0] = *(const float4*)&A[(size_t)gr * K + kn + c0];
                    pa[j][1] = *(const float4*)&A[(size_t)gr * K + kn + c0 + 4];
                } else { pa[j][0] = zf4; pa[j][1] = zf4; }
                int gn = n0 + r0 + j * 64;
                pbh[j] = (gn < Ntot) ? *(const uint4*)&BThi[(size_t)gn * K + kn + c0] : zero4;
            }
        }

        short8 ah[4], al[4];
#pragma unroll
        for (int mi = 0; mi < 4; mi++) {
            int row = wr * 64 + mi * 16 + fm;
            ah[mi] = *(const short8*)&sAh[row * LDA + q * 8];
            al[mi] = *(const short8*)&sAl[row * LDA + q * 8];
        }
#pragma unroll
        for (int ni = 0; ni < 4; ni++) {
            int nn = wc * 64 + ni * 16 + fm;
            short8 bh = *(const short8*)&sBh[nn * LDA + q * 8];
#pragma unroll
            for (int mi = 0; mi < 4; mi++) {
                acc[mi][ni] = __builtin_amdgcn_mfma_f32_16x16x32_bf16(ah[mi], bh, acc[mi][ni], 0, 0, 0);
                acc[mi][ni] = __builtin_amdgcn_mfma_f32_16x16x32_bf16(al[mi], bh, acc[mi][ni], 0, 0, 0);
            }
        }
        __syncthreads();
    }

#pragma unroll
    for (int mi = 0; mi < 4; mi++) {
#pragma unroll
        for (int ni = 0; ni < 4; ni++) {
            int colg = n0 + wc * 64 + ni * 16 + fm;
            if (colg >= Ntot) continue;
#pragma unroll
            for (int r = 0; r < 4; r++) {
                int rowg = m0 + wr * 64 + mi * 16 + q * 4 + r;
                if (rowg >= M) continue;
                float v = acc[mi][ni][r];
                if (colg < Nb) {
                    Cb[(size_t)rowg * strideB + colg] = f2bf(v);
                } else {
                    int cf = colg - Nb;
                    Cf[(size_t)rowg * strideF + cf] = v + biasf[cf];
                }
            }
        }
    }
}

// ---------------- per-node attention coefficients (bf16 xh) ----------------
__global__ __launch_bounds__(256) void alpha_kernel(const u16* __restrict__ xh,
                                                    const float* __restrict__ a_s,
                                                    const float* __restrict__ a_d,
                                                    float* __restrict__ as_o,
                                                    float* __restrict__ ad_o, int C) {
    int n = blockIdx.x;
    int w = threadIdx.x >> 6, lane = threadIdx.x & 63;
    const u16* row = xh + (size_t)n * 4 * C + (size_t)w * C;
    float ss = 0.f, sd = 0.f;
    for (int c = lane; c < C; c += 64) {
        float v = bf2f(row[c]);
        ss += v * a_s[w * C + c];
        sd += v * a_d[w * C + c];
    }
    for (int o = 32; o; o >>= 1) {
        ss += __shfl_xor(ss, o, 64);
        sd += __shfl_xor(sd, o, 64);
    }
    if (!lane) {
        as_o[n * 4 + w] = ss;
        ad_o[n * 4 + w] = sd;
    }
}

// ---------------- fused softmax stats + per-edge alpha ----------------
__global__ __launch_bounds__(256) void stats_alpha_kernel(const int* __restrict__ rowp,
                                                          const int* __restrict__ col,
                                                          const float* __restrict__ asrc,
                                                          const float* __restrict__ adst,
                                                          float* __restrict__ alphaE, int N) {
    int i = blockIdx.x * 256 + threadIdx.x;
    if (i >= N * 4) return;
    int n = i >> 2, h = i & 3;
    int r0 = rowp[n], r1 = rowp[n + 1];
    float ad = adst[i];
    float m = -3.4e38f, s = 0.f;
#pragma unroll 4
    for (int e = r0; e < r1; e++) {
        int sc = col[e];
        float l = lrelu(asrc[sc * 4 + h] + ad);
        float nm = fmaxf(m, l);
        s = s * __expf(m - nm) + __expf(l - nm);
        m = nm;
    }
    float rd = 1.f / (s + 1e-16f);
#pragma unroll 4
    for (int e = r0; e < r1; e++) {
        int sc = col[e];
        float l = lrelu(asrc[sc * 4 + h] + ad);
        alphaE[(size_t)e * 4 + h] = __expf(l - m) * rd;
    }
}

// ---------------- gather+FMA aggregate, HC=256 (layers 1/2) ----------------
// res/out may alias (in-place residual).
__global__ __launch_bounds__(256) void agg_kernel_256(const u16* __restrict__ xh,
                                                      const int* __restrict__ rowp,
                                                      const int* __restrict__ col,
                                                      const float* __restrict__ alphaE,
                                                      const float* __restrict__ bias,
                                                      const float* res,
                                                      float* out) {
    int n = blockIdx.x, tid = threadIdx.x;
    int r0 = rowp[n], deg = rowp[n + 1] - r0;
    __shared__ int s_src[64];
    __shared__ float s_al[64][4];
    __shared__ float s_part[4][HC12];
    int g = tid >> 6;
    int sub = tid & 63;
    int c = sub * 4;
    int h = sub >> 4;
    float a0 = 0.f, a1 = 0.f, a2 = 0.f, a3 = 0.f;
    for (int kb = 0; kb < deg; kb += 64) {
        int cn = min(64, deg - kb);
        __syncthreads();
        if (tid < cn) s_src[tid] = col[r0 + kb + tid];
        for (int idx = tid; idx < cn * 4; idx += 256)
            s_al[idx >> 2][idx & 3] = alphaE[(size_t)(r0 + kb) * 4 + idx];
        __syncthreads();
#pragma unroll 4
        for (int kk = g; kk < cn; kk += 4) {
            uint2 v = *(const uint2*)&xh[(size_t)s_src[kk] * HC12 + c];
            float al = s_al[kk][h];
            a0 += al * bf2f((u16)(v.x & 0xffff));
            a1 += al * bf2f((u16)(v.x >> 16));
            a2 += al * bf2f((u16)(v.y & 0xffff));
            a3 += al * bf2f((u16)(v.y >> 16));
        }
    }
    s_part[g][c] = a0; s_part[g][c + 1] = a1; s_part[g][c + 2] = a2; s_part[g][c + 3] = a3;
    __syncthreads();
    float v = s_part[0][tid] + s_part[1][tid] + s_part[2][tid] + s_part[3][tid]
              + bias[tid] + res[(size_t)n * HC12 + tid];
    out[(size_t)n * HC12 + tid] = v > 0.f ? v : expm1f(v);
}

// ---------------- layer 3 gather: HC=484, mean heads + b3 + lin3 -> d_out ----------------
__global__ __launch_bounds__(256) void agg_out_kernel(const u16* __restrict__ xh,
                                                      const int* __restrict__ rowp,
                                                      const int* __restrict__ col,
                                                      const float* __restrict__ alphaE,
                                                      const float* __restrict__ b3,
                                                      const float* __restrict__ lin3,
                                                      float* __restrict__ out) {
    int n = blockIdx.x, tid = threadIdx.x;
    int r0 = rowp[n], deg = rowp[n + 1] - r0;
    __shared__ int s_src[64];
    __shared__ float s_al[64][4];
    __shared__ float s_out[HC3];
    bool act = tid < 242;
    int c0 = 2 * tid, c1 = c0 + 1;
    int h0 = c0 >= 363 ? 3 : (c0 >= 242 ? 2 : (c0 >= 121 ? 1 : 0));
    int h1 = c1 >= 363 ? 3 : (c1 >= 242 ? 2 : (c1 >= 121 ? 1 : 0));
    float a0 = 0.f, a1 = 0.f;
    for (int kb = 0; kb < deg; kb += 64) {
        int cn = min(64, deg - kb);
        __syncthreads();
        if (tid < cn) s_src[tid] = col[r0 + kb + tid];
        for (int idx = tid; idx < cn * 4; idx += 256)
            s_al[idx >> 2][idx & 3] = alphaE[(size_t)(r0 + kb) * 4 + idx];
        __syncthreads();
        if (act) {
#pragma unroll 4
            for (int kk = 0; kk < cn; kk++) {
                u32 v = *(const u32*)&xh[(size_t)s_src[kk] * HC3 + c0];
                a0 += s_al[kk][h0] * bf2f((u16)(v & 0xffff));
                a1 += s_al[kk][h1] * bf2f((u16)(v >> 16));
            }
        }
    }
    if (act) { s_out[c0] = a0; s_out[c1] = a1; }
    __syncthreads();
    if (tid < NCLS) {
        float o = 0.25f * (s_out[tid] + s_out[NCLS + tid] + s_out[2 * NCLS + tid] + s_out[3 * NCLS + tid])
                  + b3[tid] + lin3[(size_t)n * NCLS + tid];
        out[(size_t)n * NCLS + tid] = o;
    }
}

extern "C" void kernel_launch(void* const* d_in, const int* in_sizes, int n_in,
                              void* d_out, int out_size, void* d_ws, size_t ws_size,
                              hipStream_t stream) {
    const float* x   = (const float*)d_in[0];
    const int*   ei  = (const int*)d_in[1];
    const float* W1  = (const float*)d_in[2];
    const float* a1s = (const float*)d_in[3];
    const float* a1d = (const float*)d_in[4];
    const float* b1  = (const float*)d_in[5];
    const float* l1W = (const float*)d_in[6];
    const float* l1b = (const float*)d_in[7];
    const float* W2  = (const float*)d_in[8];
    const float* a2s = (const float*)d_in[9];
    const float* a2d = (const float*)d_in[10];
    const float* b2  = (const float*)d_in[11];
    const float* W3  = (const float*)d_in[12];
    const float* a3s = (const float*)d_in[13];
    const float* a3d = (const float*)d_in[14];
    const float* b3  = (const float*)d_in[15];
    const float* l3W = (const float*)d_in[16];
    const float* l3b = (const float*)d_in[17];

    const int N = in_sizes[0] / F_IN;   // 50000
    const int E = in_sizes[1] / 2;      // 400000
    const int* srcv = ei;
    const int* dstv = ei + E;

    char* ws = (char*)d_ws;
    size_t off = 0;
    auto alloc = [&](size_t bytes) -> char* {
        char* p = ws + off;
        off += (bytes + 255) & ~(size_t)255;
        return p;
    };
    u16*   xh   = (u16*)alloc((size_t)N * HC3 * 2);      // GEMM bf16 outputs
    float* h1   = (float*)alloc((size_t)N * HC12 * 4);
    float* h2   = (float*)alloc((size_t)N * HC12 * 4);
    float* lin  = (float*)alloc((size_t)N * NCLS * 4);
    float* as_  = (float*)alloc((size_t)N * 4 * 4);
    float* ad_  = (float*)alloc((size_t)N * 4 * 4);
    int* rowp   = (int*)alloc((size_t)(N + 1) * 4);
    int* degc   = (int*)alloc((size_t)N * 4);
    int* cur    = (int*)alloc((size_t)N * 4);
    int* col    = (int*)alloc((size_t)E * 4);
    float* alphaE = (float*)alloc((size_t)E * 4 * 4);
    u16* C1h = (u16*)alloc((size_t)512 * 128 * 2);
    u16* C2h = (u16*)alloc((size_t)256 * 256 * 2);
    u16* C3h = (u16*)alloc((size_t)605 * 256 * 2);
    (void)ws_size; (void)n_in; (void)out_size;

    // ---- CSR build ----
    hipMemsetAsync(degc, 0, (size_t)N * 4, stream);
    hipMemsetAsync(cur, 0, (size_t)N * 4, stream);
    hist_kernel<<<(E + 255) / 256, 256, 0, stream>>>(dstv, degc, E);
    scan_kernel<<<1, 1024, 0, stream>>>(degc, rowp, N);
    scatter_kernel<<<(E + 255) / 256, 256, 0, stream>>>(srcv, dstv, rowp, cur, col, E);

    // ---- fused weight transpose/round ----
    splitT_all_kernel<<<(285952 + 255) / 256, 256, 0, stream>>>(W1, l1W, W2, W3, l3W,
                                                                C1h, C2h, C3h);

    int ny = (N + BM - 1) / BM;
    int sgrid = (N * 4 + 255) / 256;

    // ---- layer 1 ----
    gemm_mfma_split<<<4 * ny, 256, 0, stream>>>(x, C1h, N, F_IN, 512, 4, ny,
                                                256, xh, 256, h1, l1b, 256);
    alpha_kernel<<<N, 256, 0, stream>>>(xh, a1s, a1d, as_, ad_, 64);
    stats_alpha_kernel<<<sgrid, 256, 0, stream>>>(rowp, col, as_, ad_, alphaE, N);
    agg_kernel_256<<<N, 256, 0, stream>>>(xh, rowp, col, alphaE, b1, h1, h1);

    // ---- layer 2 ----
    gemm_mfma_split<<<2 * ny, 256, 0, stream>>>(h1, C2h, N, HC12, 256, 2, ny,
                                                256, xh, 256, nullptr, nullptr, 0);
    alpha_kernel<<<N, 256, 0, stream>>>(xh, a2s, a2d, as_, ad_, 64);
    stats_alpha_kernel<<<sgrid, 256, 0, stream>>>(rowp, col, as_, ad_, alphaE, N);
    agg_kernel_256<<<N, 256, 0, stream>>>(xh, rowp, col, alphaE, b2, h1, h2);

    // ---- layer 3 ----
    gemm_mfma_split<<<5 * ny, 256, 0, stream>>>(h2, C3h, N, HC12, 605, 5, ny,
                                                484, xh, 484, lin, l3b, NCLS);
    alpha_kernel<<<N, 256, 0, stream>>>(xh, a3s, a3d, as_, ad_, NCLS);
    stats_alpha_kernel<<<sgrid, 256, 0, stream>>>(rowp, col, as_, ad_, alphaE, N);
    agg_out_kernel<<<N, 256, 0, stream>>>(xh, rowp, col, alphaE, b3, lin, (float*)d_out);
}